// Round 7
// baseline (767.979 us; speedup 1.0000x reference)
//
#include <hip/hip_runtime.h>
#include <hip/hip_cooperative_groups.h>
#include <stdint.h>

namespace cg = cooperative_groups;

typedef unsigned int u32;
typedef unsigned long long u64;

#define MOD_P 2013265921u

// uint2 table offsets (index in uint2 units): (value, shoup) pairs
#define T_A      0        // w^{(i>>7)*(i&127)}        [ka][jc] product table, 16384
#define T_B      16384    // (w^128)^{(i>>7)*(i&127)}  [kb][jc] product table, 16384
#define T_W128P  32768    // (w^128)^i, i<16384
#define T_RP     49152    // (w^16384)^i, i<64  (order-128 stage roots)
#define T_CLP    49216    // c^i, i<16384       (coset low)
#define T_CHP    65600    // c^(16384 i), i<128 (coset high)
#define T_NINV   65728    // (n^-1)

__device__ __forceinline__ u32 mul64mod(u32 a, u32 b){ return (u32)((u64)a * b % MOD_P); }

__device__ u32 powmod(u32 b, u32 e){
  u32 r = 1;
  while (e){ if (e & 1) r = mul64mod(r, b); b = mul64mod(b, b); e >>= 1; }
  return r;
}

__device__ __forceinline__ u32 shoup_of(u32 v){ return (u32)(((u64)v << 32) / MOD_P); }

// reduce a in [0,2P) to [0,P): unsigned-wrap min trick (v_sub + v_min_u32)
__device__ __forceinline__ u32 redP(u32 a){
  u32 b = a - MOD_P;
  return b < a ? b : a;
}

// Shoup modular multiply; valid for ANY a < 2^32 (w < P): r = a*w mod P in [0,P)
__device__ __forceinline__ u32 mul_shoup(u32 a, uint2 t){
  u32 q = __umulhi(a, t.y);
  u32 r = a * t.x - q * MOD_P;          // exact mod 2^32, true value < 2P
  return redP(r);
}

__device__ __forceinline__ constexpr int rev4(int m){
  return ((m&1)<<3) | ((m&2)<<1) | ((m&4)>>1) | ((m&8)>>3);
}

// DIF butterfly: (x,y) -> (x+y mod P, (x-y)*t mod P); inputs in [0,P)
__device__ __forceinline__ void bf(u32 &x, u32 &y, uint2 t){
  u32 s = redP(x + y);
  u32 d = x - y + MOD_P;                // in (0,2P) — mul_shoup absorbs
  x = s; y = mul_shoup(d, t);
}
// last stage, twiddle=1: y left in [0,2P) (consumer must absorb or redP)
__device__ __forceinline__ void bf0(u32 &x, u32 &y){
  u32 s = redP(x + y);
  u32 d = x - y + MOD_P;
  x = s; y = d;
}

// phase-1: thread rows r = b + 8m (m=0..15), DIF stages h=64,32,16,8
__device__ __forceinline__ void stages_p1(u32 v[16], int b, const uint2* __restrict__ twl){
  #pragma unroll
  for (int m = 0; m < 8; ++m) bf(v[m], v[m+8], twl[b + 8*m]);               // s=6
  #pragma unroll
  for (int g = 0; g < 2; ++g)
    #pragma unroll
    for (int m = 0; m < 4; ++m) bf(v[g*8+m], v[g*8+m+4], twl[(b + 8*m) << 1]); // s=5
  #pragma unroll
  for (int g = 0; g < 4; ++g)
    #pragma unroll
    for (int m = 0; m < 2; ++m) bf(v[g*4+m], v[g*4+m+2], twl[(b + 8*m) << 2]); // s=4
  #pragma unroll
  for (int k = 0; k < 8; ++k) bf(v[2*k], v[2*k+1], twl[b << 3]);            // s=3
}
// phase-2: thread rows r = 16b + m, DIF stages h=4,2,1
__device__ __forceinline__ void stages_p2(u32 v[16], const uint2* __restrict__ twl){
  #pragma unroll
  for (int g = 0; g < 2; ++g)
    #pragma unroll
    for (int m = 0; m < 4; ++m) bf(v[g*8+m], v[g*8+m+4], twl[m << 4]);      // s=2
  #pragma unroll
  for (int g = 0; g < 4; ++g)
    #pragma unroll
    for (int m = 0; m < 2; ++m) bf(v[g*4+m], v[g*4+m+2], twl[m << 5]);      // s=1
  #pragma unroll
  for (int k = 0; k < 8; ++k) bf0(v[2*k], v[2*k+1]);                        // s=0 (e=0)
}

// LDS swizzle for pass C tile [row=jc(128)][col=ka(128)]: 2-way max aliasing
__device__ __forceinline__ int cidx(int row, int a){
  return (row << 7) | (a ^ (row >> 2));
}

// ---------------- table generation (per launch; reads direction flag) -------
extern "C" __global__ void k_gen(uint2* __restrict__ tw, const int* __restrict__ f_intt){
  const int idx = blockIdx.x * 256 + threadIdx.x;   // 0..16383
  const int intt = f_intt[0];
  u32 w = powmod(31u, (MOD_P - 1) >> 21);     // primitive 2^21-th root
  if (intt) w = powmod(w, MOD_P - 2);
  const u32 w128 = powmod(w, 128u);
  const int hi = idx >> 7, lo = idx & 127;

  u32 a = powmod(w, (u32)(hi * lo));
  tw[T_A + idx] = make_uint2(a, shoup_of(a));
  u32 b = powmod(w128, (u32)(hi * lo));
  tw[T_B + idx] = make_uint2(b, shoup_of(b));
  u32 v2 = powmod(w128, (u32)idx);
  tw[T_W128P + idx] = make_uint2(v2, shoup_of(v2));
  u32 c = intt ? powmod(7u, MOD_P - 2) : 7u;
  u32 cv = powmod(c, (u32)idx);
  tw[T_CLP + idx] = make_uint2(cv, shoup_of(cv));
  if (idx < 128){
    u32 h = powmod(c, (u32)idx << 14);
    tw[T_CHP + idx] = make_uint2(h, shoup_of(h));
  }
  if (idx < 64){
    u32 rv = powmod(powmod(w, 1u << 14), (u32)idx);
    tw[T_RP + idx] = make_uint2(rv, shoup_of(rv));
  }
  if (idx == 0){
    u32 ninv = powmod(1u << 21, MOD_P - 2);
    tw[T_NINV] = make_uint2(ninv, shoup_of(ninv));
  }
}

// =================== fused persistent cooperative kernel ====================
extern "C" __global__ void __launch_bounds__(1024, 8) k_fused(
    const u32* __restrict__ x, u32* __restrict__ y, const uint2* __restrict__ tw,
    const int* __restrict__ f_intt, const int* __restrict__ f_coset, int nunits)
{
  cg::grid_group grid = cg::this_grid();
  __shared__ u32 lds[16384];
  const int t = threadIdx.x;
  const int jc = t & 127;
  const int b = __builtin_amdgcn_readfirstlane(t >> 7);   // 0..7, wave-uniform
  const int rb = ((b&1)<<2) | (b&2) | ((b&4)>>2);         // rev3(b)
  const uint2* twl = tw + T_RP;
  const int nwg = gridDim.x;
  const int intt = f_intt[0];
  const int coset = f_coset[0];
  const bool pre = (intt == 0) && (coset != 0);

  // ---------------- pass A: NTT over ja (stride 16384), x -> y --------------
  for (int u = blockIdx.x; u < nunits; u += nwg){
    __syncthreads();
    const int jb = u & 127;
    const int batch = u >> 7;
    const u32* xb = x + ((size_t)batch << 21);
    u32* yb = y + ((size_t)batch << 21);
    u32 v[16];
    #pragma unroll
    for (int m = 0; m < 16; ++m){
      u32 a = xb[((size_t)(b + 8*m) << 14) + (jb << 7) + jc];
      v[m] = redP(a);
    }
    if (pre){
      uint2 cl = tw[T_CLP + (jb << 7) + jc];
      #pragma unroll
      for (int m = 0; m < 16; ++m){
        v[m] = mul_shoup(v[m], cl);
        v[m] = mul_shoup(v[m], tw[T_CHP + b + 8*m]);
      }
    }
    stages_p1(v, b, twl);
    #pragma unroll
    for (int m = 0; m < 16; ++m) lds[((b + 8*m) << 7) | jc] = v[m];
    __syncthreads();
    #pragma unroll
    for (int m = 0; m < 16; ++m) v[m] = lds[((16*b + m) << 7) | jc];
    stages_p2(v, twl);
    #pragma unroll
    for (int m = 0; m < 16; ++m){
      const int ka = (rev4(m) << 3) | rb;                    // br7(16b+m)
      u32 vv = mul_shoup(v[m], tw[T_A + (ka << 7) + jc]);    // absorbs [0,2P)
      vv = mul_shoup(vv, tw[T_W128P + ka * jb]);             // wave-uniform
      yb[((size_t)ka << 14) + (jb << 7) + jc] = vv;
    }
  }
  __threadfence();
  grid.sync();

  // ---------------- pass B: NTT over jb (contiguous slab, in-place) ---------
  for (int u = blockIdx.x; u < nunits; u += nwg){
    __syncthreads();
    const int ka = u & 127;
    const int batch = u >> 7;
    u32* yb = y + ((size_t)batch << 21) + ((size_t)ka << 14);
    u32 v[16];
    #pragma unroll
    for (int m = 0; m < 16; ++m) v[m] = yb[((b + 8*m) << 7) + jc];
    stages_p1(v, b, twl);
    #pragma unroll
    for (int m = 0; m < 16; ++m) lds[((b + 8*m) << 7) | jc] = v[m];
    __syncthreads();
    #pragma unroll
    for (int m = 0; m < 16; ++m) v[m] = lds[((16*b + m) << 7) | jc];
    stages_p2(v, twl);
    #pragma unroll
    for (int m = 0; m < 16; ++m){
      const int kb = (rev4(m) << 3) | rb;
      u32 vv = mul_shoup(v[m], tw[T_B + (kb << 7) + jc]);    // absorbs [0,2P)
      yb[(kb << 7) + jc] = vv;
    }
  }
  __threadfence();
  grid.sync();

  // ------- pass C: NTT over jc + in-place plane transpose to final order ----
  for (int u = blockIdx.x; u < nunits; u += nwg){
    __syncthreads();
    const int kb = u & 127;
    const int batch = u >> 7;
    u32* yb = y + ((size_t)batch << 21);
    const u32* base = yb + (kb << 7);
    {   // stage-in: transpose [ka][jc] -> LDS[jc][ka]
      const int q = t & 31;                // jc quad
      const int rr = t >> 5;               // 0..31
      #pragma unroll
      for (int i = 0; i < 4; ++i){
        int kaL = rr + 32*i;
        uint4 v4 = *(const uint4*)(base + ((size_t)kaL << 14) + (q << 2));
        lds[cidx(4*q+0, kaL)] = v4.x;
        lds[cidx(4*q+1, kaL)] = v4.y;
        lds[cidx(4*q+2, kaL)] = v4.z;
        lds[cidx(4*q+3, kaL)] = v4.w;
      }
    }
    __syncthreads();
    const int a = jc;
    u32 v[16];
    #pragma unroll
    for (int m = 0; m < 16; ++m) v[m] = lds[cidx(b + 8*m, a)];
    stages_p1(v, b, twl);
    #pragma unroll
    for (int m = 0; m < 16; ++m) lds[cidx(b + 8*m, a)] = v[m];
    __syncthreads();
    #pragma unroll
    for (int m = 0; m < 16; ++m) v[m] = lds[cidx(16*b + m, a)];
    stages_p2(v, twl);
    #pragma unroll
    for (int m = 0; m < 16; ++m){
      const int kc = (rev4(m) << 3) | rb;
      u32 vv = v[m];
      if (intt){
        vv = mul_shoup(vv, tw[T_NINV]);                      // absorbs [0,2P)
        if (coset){
          vv = mul_shoup(vv, tw[T_CLP + (kb << 7) + a]);
          vv = mul_shoup(vv, tw[T_CHP + kc]);
        }
      } else {
        vv = redP(vv);                                       // bf0 leaves [0,2P)
      }
      // final output never re-read on device: bypass L3 to preserve residency
      __builtin_nontemporal_store(vv, yb + ((size_t)kc << 14) + (kb << 7) + a);
    }
  }
}

// =================== non-cooperative fallback kernels =======================
extern "C" __global__ void __launch_bounds__(1024, 8) k_passA(
    const u32* __restrict__ x, u32* __restrict__ y, const uint2* __restrict__ tw,
    const int* __restrict__ f_intt, const int* __restrict__ f_coset)
{
  __shared__ u32 lds[16384];
  const int wg = blockIdx.x;
  const int jb = wg & 127;
  const int batch = wg >> 7;
  const int t = threadIdx.x;
  const int jc = t & 127;
  const int b = __builtin_amdgcn_readfirstlane(t >> 7);
  const u32* xb = x + ((size_t)batch << 21);
  u32* yb = y + ((size_t)batch << 21);
  const uint2* twl = tw + T_RP;
  u32 v[16];
  #pragma unroll
  for (int m = 0; m < 16; ++m){
    u32 a = xb[((size_t)(b + 8*m) << 14) + (jb << 7) + jc];
    v[m] = redP(a);
  }
  if ((f_intt[0] == 0) && (f_coset[0] != 0)){
    uint2 cl = tw[T_CLP + (jb << 7) + jc];
    #pragma unroll
    for (int m = 0; m < 16; ++m){
      v[m] = mul_shoup(v[m], cl);
      v[m] = mul_shoup(v[m], tw[T_CHP + b + 8*m]);
    }
  }
  stages_p1(v, b, twl);
  #pragma unroll
  for (int m = 0; m < 16; ++m) lds[((b + 8*m) << 7) | jc] = v[m];
  __syncthreads();
  #pragma unroll
  for (int m = 0; m < 16; ++m) v[m] = lds[((16*b + m) << 7) | jc];
  stages_p2(v, twl);
  const int rb = ((b&1)<<2) | (b&2) | ((b&4)>>2);
  #pragma unroll
  for (int m = 0; m < 16; ++m){
    const int ka = (rev4(m) << 3) | rb;
    u32 vv = mul_shoup(v[m], tw[T_A + (ka << 7) + jc]);
    vv = mul_shoup(vv, tw[T_W128P + ka * jb]);
    yb[((size_t)ka << 14) + (jb << 7) + jc] = vv;
  }
}

extern "C" __global__ void __launch_bounds__(1024, 8) k_passB(
    u32* __restrict__ y, const uint2* __restrict__ tw)
{
  __shared__ u32 lds[16384];
  const int wg = blockIdx.x;
  const int ka = wg & 127;
  const int batch = wg >> 7;
  const int t = threadIdx.x;
  const int jc = t & 127;
  const int b = __builtin_amdgcn_readfirstlane(t >> 7);
  u32* yb = y + ((size_t)batch << 21) + ((size_t)ka << 14);
  const uint2* twl = tw + T_RP;
  u32 v[16];
  #pragma unroll
  for (int m = 0; m < 16; ++m) v[m] = yb[((b + 8*m) << 7) + jc];
  stages_p1(v, b, twl);
  #pragma unroll
  for (int m = 0; m < 16; ++m) lds[((b + 8*m) << 7) | jc] = v[m];
  __syncthreads();
  #pragma unroll
  for (int m = 0; m < 16; ++m) v[m] = lds[((16*b + m) << 7) | jc];
  stages_p2(v, twl);
  const int rb = ((b&1)<<2) | (b&2) | ((b&4)>>2);
  #pragma unroll
  for (int m = 0; m < 16; ++m){
    const int kb = (rev4(m) << 3) | rb;
    u32 vv = mul_shoup(v[m], tw[T_B + (kb << 7) + jc]);
    yb[(kb << 7) + jc] = vv;
  }
}

extern "C" __global__ void __launch_bounds__(1024, 8) k_passC(
    u32* __restrict__ y, const uint2* __restrict__ tw,
    const int* __restrict__ f_intt, const int* __restrict__ f_coset)
{
  __shared__ u32 lds[16384];
  const int wg = blockIdx.x;
  const int kb = wg & 127;
  const int batch = wg >> 7;
  u32* yb = y + ((size_t)batch << 21);
  const u32* base = yb + (kb << 7);
  const int t = threadIdx.x;
  {
    const int q = t & 31;
    const int rr = t >> 5;
    #pragma unroll
    for (int i = 0; i < 4; ++i){
      int kaL = rr + 32*i;
      uint4 v4 = *(const uint4*)(base + ((size_t)kaL << 14) + (q << 2));
      lds[cidx(4*q+0, kaL)] = v4.x;
      lds[cidx(4*q+1, kaL)] = v4.y;
      lds[cidx(4*q+2, kaL)] = v4.z;
      lds[cidx(4*q+3, kaL)] = v4.w;
    }
  }
  __syncthreads();
  const int a = t & 127;
  const int b = __builtin_amdgcn_readfirstlane(t >> 7);
  const uint2* twl = tw + T_RP;
  u32 v[16];
  #pragma unroll
  for (int m = 0; m < 16; ++m) v[m] = lds[cidx(b + 8*m, a)];
  stages_p1(v, b, twl);
  #pragma unroll
  for (int m = 0; m < 16; ++m) lds[cidx(b + 8*m, a)] = v[m];
  __syncthreads();
  #pragma unroll
  for (int m = 0; m < 16; ++m) v[m] = lds[cidx(16*b + m, a)];
  stages_p2(v, twl);
  const int rb = ((b&1)<<2) | (b&2) | ((b&4)>>2);
  const int intt = f_intt[0];
  const int coset = f_coset[0];
  #pragma unroll
  for (int m = 0; m < 16; ++m){
    const int kc = (rev4(m) << 3) | rb;
    u32 vv = v[m];
    if (intt){
      vv = mul_shoup(vv, tw[T_NINV]);
      if (coset){
        vv = mul_shoup(vv, tw[T_CLP + (kb << 7) + a]);
        vv = mul_shoup(vv, tw[T_CHP + kc]);
      }
    } else {
      vv = redP(vv);
    }
    yb[((size_t)kc << 14) + (kb << 7) + a] = vv;
  }
}

extern "C" void kernel_launch(void* const* d_in, const int* in_sizes, int n_in,
                              void* d_out, int out_size, void* d_ws, size_t ws_size,
                              hipStream_t stream)
{
  const u32* x = (const u32*)d_in[0];
  const int* f_intt  = (const int*)d_in[1];
  const int* f_coset = (const int*)d_in[2];
  u32* y   = (u32*)d_out;
  uint2* tw = (uint2*)d_ws;
  const int batch = in_sizes[0] >> 21;     // 8
  int nunits = batch << 7;                 // 1024 tile-units per pass

  k_gen<<<64, 256, 0, stream>>>(tw, f_intt);

  int gwg = nunits < 512 ? nunits : 512;   // 2 WG/CU resident -> persistent
  void* args[] = {(void*)&x, (void*)&y, (void*)&tw,
                  (void*)&f_intt, (void*)&f_coset, (void*)&nunits};
  hipError_t err = hipLaunchCooperativeKernel((const void*)k_fused,
                                              dim3(gwg), dim3(1024),
                                              args, 0, stream);
  if (err != hipSuccess){
    // deterministic fallback: 3-kernel pipeline (same math)
    k_passA<<<nunits, 1024, 0, stream>>>(x, y, tw, f_intt, f_coset);
    k_passB<<<nunits, 1024, 0, stream>>>(y, tw);
    k_passC<<<nunits, 1024, 0, stream>>>(y, tw, f_intt, f_coset);
  }
}

// Round 8
// 103.298 us; speedup vs baseline: 7.4346x; 7.4346x over previous
//
#include <hip/hip_runtime.h>
#include <stdint.h>

typedef unsigned int u32;
typedef unsigned long long u64;

#define MOD_P 2013265921u

// uint2 table offsets (index in uint2 units): (value, shoup) pairs
#define T_A      0        // w^{(i>>7)*(i&127)}        [ka][jc] product table, 16384
#define T_B      16384    // (w^128)^{(i>>7)*(i&127)}  [kb][jc] product table, 16384
#define T_W128P  32768    // (w^128)^i, i<16384
#define T_RP     49152    // (w^16384)^i, i<64  (order-128 stage roots)
#define T_CLP    49216    // c^i, i<16384       (coset low)
#define T_CHP    65600    // c^(16384 i), i<128 (coset high)
#define T_NINV   65728    // (n^-1)

__device__ __forceinline__ u32 mul64mod(u32 a, u32 b){ return (u32)((u64)a * b % MOD_P); }

__device__ u32 powmod(u32 b, u32 e){
  u32 r = 1;
  while (e){ if (e & 1) r = mul64mod(r, b); b = mul64mod(b, b); e >>= 1; }
  return r;
}

__device__ __forceinline__ u32 shoup_of(u32 v){ return (u32)(((u64)v << 32) / MOD_P); }

// reduce a in [0,2P) to [0,P): v_sub + v_min_u32 (unsigned-wrap min trick)
__device__ __forceinline__ u32 redP(u32 a){
  u32 b = a - MOD_P;
  return b < a ? b : a;
}

// Shoup modular multiply; valid for ANY a < 2^32 (w < P): r = a*w mod P in [0,P)
__device__ __forceinline__ u32 mul_shoup(u32 a, uint2 t){
  u32 q = __umulhi(a, t.y);
  u32 r = a * t.x - q * MOD_P;          // exact mod 2^32, true value < 2P
  return redP(r);
}

__device__ __forceinline__ constexpr int rev4(int m){
  return ((m&1)<<3) | ((m&2)<<1) | ((m&4)>>1) | ((m&8)>>3);
}

// DIF butterfly: (x,y) -> (x+y mod P, (x-y)*t mod P); inputs in [0,P)
__device__ __forceinline__ void bf(u32 &x, u32 &y, uint2 t){
  u32 s = redP(x + y);
  u32 d = x - y + MOD_P;                // in (0,2P) — mul_shoup absorbs
  x = s; y = mul_shoup(d, t);
}
// last stage, twiddle=1: y left in [0,2P) (consumer must absorb or redP)
__device__ __forceinline__ void bf0(u32 &x, u32 &y){
  u32 s = redP(x + y);
  u32 d = x - y + MOD_P;
  x = s; y = d;
}

// phase-1: thread rows r = b + 8m (m=0..15), DIF stages h=64,32,16,8
__device__ __forceinline__ void stages_p1(u32 v[16], int b, const uint2* __restrict__ twl){
  #pragma unroll
  for (int m = 0; m < 8; ++m) bf(v[m], v[m+8], twl[b + 8*m]);               // s=6
  #pragma unroll
  for (int g = 0; g < 2; ++g)
    #pragma unroll
    for (int m = 0; m < 4; ++m) bf(v[g*8+m], v[g*8+m+4], twl[(b + 8*m) << 1]); // s=5
  #pragma unroll
  for (int g = 0; g < 4; ++g)
    #pragma unroll
    for (int m = 0; m < 2; ++m) bf(v[g*4+m], v[g*4+m+2], twl[(b + 8*m) << 2]); // s=4
  #pragma unroll
  for (int k = 0; k < 8; ++k) bf(v[2*k], v[2*k+1], twl[b << 3]);            // s=3
}
// phase-2: thread rows r = 16b + m, DIF stages h=4,2,1
__device__ __forceinline__ void stages_p2(u32 v[16], const uint2* __restrict__ twl){
  #pragma unroll
  for (int g = 0; g < 2; ++g)
    #pragma unroll
    for (int m = 0; m < 4; ++m) bf(v[g*8+m], v[g*8+m+4], twl[m << 4]);      // s=2
  #pragma unroll
  for (int g = 0; g < 4; ++g)
    #pragma unroll
    for (int m = 0; m < 2; ++m) bf(v[g*4+m], v[g*4+m+2], twl[m << 5]);      // s=1
  #pragma unroll
  for (int k = 0; k < 8; ++k) bf0(v[2*k], v[2*k+1]);                        // s=0 (e=0)
}

// LDS swizzle for pass C tile [row=jc(128)][col=ka(128)]: 2-way max aliasing
__device__ __forceinline__ int cidx(int row, int a){
  return (row << 7) | (a ^ (row >> 2));
}

// ------------- table generation: ONE powmod per thread, 257 WGs -------------
// w = 31^960 (order 2^21); w^e with intt => exponent flip e -> 2^21-e.
extern "C" __global__ void k_gen(uint2* __restrict__ tw, const int* __restrict__ f_intt){
  const u32 tid = blockIdx.x * 256 + threadIdx.x;
  const int intt = f_intt[0];
  const u32 MASK = (1u << 21) - 1;
  u32 v; int dst;
  if (tid < 16384){                       // T_A: w^{hi*lo}
    u32 e = (tid >> 7) * (tid & 127);
    if (intt) e = ((1u<<21) - e) & MASK;
    v = powmod(31u, 960u * e); dst = T_A + tid;
  } else if (tid < 32768){                // T_B: w^{128*hi*lo mod 2^21}
    u32 i = tid - 16384;
    u32 e = (((i >> 7) * (i & 127)) << 7) & MASK;
    if (intt) e = ((1u<<21) - e) & MASK;
    v = powmod(31u, 960u * e); dst = T_B + i;
  } else if (tid < 49152){                // T_W128P: w^{128 i mod 2^21}
    u32 i = tid - 32768;
    u32 e = (i << 7) & MASK;
    if (intt) e = ((1u<<21) - e) & MASK;
    v = powmod(31u, 960u * e); dst = T_W128P + i;
  } else if (tid < 65536){                // T_CLP: c^i (c=7 or 7^-1)
    u32 i = tid - 49152;
    v = intt ? powmod(7u, (MOD_P - 1 - i) % (MOD_P - 1)) : powmod(7u, i);
    dst = T_CLP + i;
  } else if (tid < 65664){                // T_CHP: c^{i<<14}
    u32 e = (tid - 65536) << 14;
    v = intt ? powmod(7u, MOD_P - 1 - e) : powmod(7u, e);
    dst = T_CHP + (tid - 65536);
  } else if (tid < 65728){                // T_RP: w^{i<<14}
    u32 e = ((tid - 65664) << 14) & MASK;
    if (intt) e = ((1u<<21) - e) & MASK;
    v = powmod(31u, 960u * e); dst = T_RP + (tid - 65664);
  } else if (tid == 65728){               // NINV
    v = powmod(1u << 21, MOD_P - 2); dst = T_NINV;
  } else return;
  tw[dst] = make_uint2(v, shoup_of(v));
}

// ---------------- pass A: NTT over ja (stride 16384), d_in -> d_out ---------
// grid: batch*128, WG=(batch, jb); uint4 stage-in, 16 elems/thread in reg
extern "C" __global__ void __launch_bounds__(1024, 8) k_passA(
    const u32* __restrict__ x, u32* __restrict__ y, const uint2* __restrict__ tw,
    const int* __restrict__ f_intt, const int* __restrict__ f_coset)
{
  __shared__ u32 lds[16384];              // [128 ja][128 jc] natural
  const int wg = blockIdx.x;
  const int jb = wg & 127;
  const int batch = wg >> 7;
  const int t = threadIdx.x;
  const u32* xb = x + ((size_t)batch << 21) + (jb << 7);
  u32* yb = y + ((size_t)batch << 21);
  const uint2* twl = tw + T_RP;
  {   // stage-in: uint4 loads (512B segments), normalize to [0,P)
    const int q = t & 31, rr = t >> 5;    // q: jc-quad, rr: 0..31
    #pragma unroll
    for (int i = 0; i < 4; ++i){
      const int ja = rr + 32*i;
      uint4 v4 = *(const uint4*)(xb + ((size_t)ja << 14) + (q << 2));
      u32* d = &lds[(ja << 7) | (q << 2)];
      d[0] = redP(v4.x); d[1] = redP(v4.y); d[2] = redP(v4.z); d[3] = redP(v4.w);
    }
  }
  __syncthreads();
  const int jc = t & 127;
  const int b = __builtin_amdgcn_readfirstlane(t >> 7);   // 0..7, wave-uniform
  u32 v[16];
  #pragma unroll
  for (int m = 0; m < 16; ++m) v[m] = lds[((b + 8*m) << 7) | jc];
  if ((f_intt[0] == 0) && (f_coset[0] != 0)){
    uint2 cl = tw[T_CLP + (jb << 7) + jc];
    #pragma unroll
    for (int m = 0; m < 16; ++m){
      v[m] = mul_shoup(v[m], cl);
      v[m] = mul_shoup(v[m], tw[T_CHP + b + 8*m]);
    }
  }
  stages_p1(v, b, twl);
  #pragma unroll
  for (int m = 0; m < 16; ++m) lds[((b + 8*m) << 7) | jc] = v[m];
  __syncthreads();
  #pragma unroll
  for (int m = 0; m < 16; ++m) v[m] = lds[((16*b + m) << 7) | jc];
  stages_p2(v, twl);
  const int rb = ((b&1)<<2) | (b&2) | ((b&4)>>2);          // rev3(b)
  #pragma unroll
  for (int m = 0; m < 16; ++m){
    const int ka = (rev4(m) << 3) | rb;                    // br7(16b+m)
    u32 vv = mul_shoup(v[m], tw[T_A + (ka << 7) + jc]);    // absorbs [0,2P)
    vv = mul_shoup(vv, tw[T_W128P + ka * jb]);             // wave-uniform
    yb[((size_t)ka << 14) + (jb << 7) + jc] = vv;
  }
}

// ---------------- pass B: NTT over jb (contiguous slab, in-place) -----------
extern "C" __global__ void __launch_bounds__(1024, 8) k_passB(
    u32* __restrict__ y, const uint2* __restrict__ tw)
{
  __shared__ u32 lds[16384];
  const int wg = blockIdx.x;
  const int ka = wg & 127;
  const int batch = wg >> 7;
  const int t = threadIdx.x;
  u32* yb = y + ((size_t)batch << 21) + ((size_t)ka << 14);
  const uint2* twl = tw + T_RP;
  {   // stage-in: fully contiguous uint4 copy (1KB/wave-load)
    const uint4* s4 = (const uint4*)yb;
    uint4* l4 = (uint4*)lds;
    #pragma unroll
    for (int i = 0; i < 4; ++i) l4[t + 1024*i] = s4[t + 1024*i];
  }
  __syncthreads();
  const int jc = t & 127;
  const int b = __builtin_amdgcn_readfirstlane(t >> 7);
  u32 v[16];
  #pragma unroll
  for (int m = 0; m < 16; ++m) v[m] = lds[((b + 8*m) << 7) | jc];
  stages_p1(v, b, twl);
  #pragma unroll
  for (int m = 0; m < 16; ++m) lds[((b + 8*m) << 7) | jc] = v[m];
  __syncthreads();
  #pragma unroll
  for (int m = 0; m < 16; ++m) v[m] = lds[((16*b + m) << 7) | jc];
  stages_p2(v, twl);
  const int rb = ((b&1)<<2) | (b&2) | ((b&4)>>2);
  #pragma unroll
  for (int m = 0; m < 16; ++m){
    const int kb = (rev4(m) << 3) | rb;
    u32 vv = mul_shoup(v[m], tw[T_B + (kb << 7) + jc]);    // absorbs [0,2P)
    yb[(kb << 7) + jc] = vv;
  }
}

// ------- pass C: NTT over jc + in-place plane transpose to final order ------
extern "C" __global__ void __launch_bounds__(1024, 8) k_passC(
    u32* __restrict__ y, const uint2* __restrict__ tw,
    const int* __restrict__ f_intt, const int* __restrict__ f_coset)
{
  __shared__ u32 lds[16384];
  const int wg = blockIdx.x;
  const int kb = wg & 127;
  const int batch = wg >> 7;
  u32* yb = y + ((size_t)batch << 21);
  const u32* base = yb + (kb << 7);
  const int t = threadIdx.x;
  {   // stage-in: transpose [ka][jc] -> LDS[jc][ka], swizzled
    const int q = t & 31;
    const int rr = t >> 5;
    #pragma unroll
    for (int i = 0; i < 4; ++i){
      int kaL = rr + 32*i;
      uint4 v4 = *(const uint4*)(base + ((size_t)kaL << 14) + (q << 2));
      lds[cidx(4*q+0, kaL)] = v4.x;
      lds[cidx(4*q+1, kaL)] = v4.y;
      lds[cidx(4*q+2, kaL)] = v4.z;
      lds[cidx(4*q+3, kaL)] = v4.w;
    }
  }
  __syncthreads();
  const int a = t & 127;
  const int b = __builtin_amdgcn_readfirstlane(t >> 7);
  const uint2* twl = tw + T_RP;
  u32 v[16];
  #pragma unroll
  for (int m = 0; m < 16; ++m) v[m] = lds[cidx(b + 8*m, a)];
  stages_p1(v, b, twl);
  #pragma unroll
  for (int m = 0; m < 16; ++m) lds[cidx(b + 8*m, a)] = v[m];
  __syncthreads();
  #pragma unroll
  for (int m = 0; m < 16; ++m) v[m] = lds[cidx(16*b + m, a)];
  stages_p2(v, twl);
  const int rb = ((b&1)<<2) | (b&2) | ((b&4)>>2);
  const int intt = f_intt[0];
  const int coset = f_coset[0];
  #pragma unroll
  for (int m = 0; m < 16; ++m){
    const int kc = (rev4(m) << 3) | rb;
    u32 vv = v[m];
    if (intt){
      vv = mul_shoup(vv, tw[T_NINV]);                      // absorbs [0,2P)
      if (coset){
        vv = mul_shoup(vv, tw[T_CLP + (kb << 7) + a]);
        vv = mul_shoup(vv, tw[T_CHP + kc]);
      }
    } else {
      vv = redP(vv);                                       // bf0 leaves [0,2P)
    }
    // final output is dead data for the next replay: keep it out of L3
    __builtin_nontemporal_store(vv, yb + ((size_t)kc << 14) + (kb << 7) + a);
  }
}

extern "C" void kernel_launch(void* const* d_in, const int* in_sizes, int n_in,
                              void* d_out, int out_size, void* d_ws, size_t ws_size,
                              hipStream_t stream)
{
  const u32* x = (const u32*)d_in[0];
  const int* f_intt  = (const int*)d_in[1];
  const int* f_coset = (const int*)d_in[2];
  u32* y   = (u32*)d_out;
  uint2* tw = (uint2*)d_ws;
  const int batch = in_sizes[0] >> 21;     // 8
  const int nwg = batch << 7;              // 1024 workgroups per pass

  k_gen  <<<257,  256, 0, stream>>>(tw, f_intt);
  k_passA<<<nwg, 1024, 0, stream>>>(x, y, tw, f_intt, f_coset);
  k_passB<<<nwg, 1024, 0, stream>>>(y, tw);
  k_passC<<<nwg, 1024, 0, stream>>>(y, tw, f_intt, f_coset);
}

// Round 9
// 99.728 us; speedup vs baseline: 7.7007x; 1.0358x over previous
//
#include <hip/hip_runtime.h>
#include <stdint.h>

typedef unsigned int u32;
typedef unsigned long long u64;

#define MOD_P 2013265921u

// uint2 table offsets (index in uint2 units): (value, shoup) pairs
#define T_A      0        // w^{(i>>7)*(i&127)}        [ka][jc] product table, 16384
#define T_B      16384    // (w^128)^{(i>>7)*(i&127)}  [kb][jc] product table, 16384
#define T_W128P  32768    // (w^128)^i, i<16384
#define T_RP     49152    // (w^16384)^i, i<64  (order-128 stage roots)
#define T_CLP    49216    // c^i, i<16384       (coset low)
#define T_CHP    65600    // c^(16384 i), i<128 (coset high)
#define T_NINV   65728    // (n^-1)

__device__ __forceinline__ u32 mul64mod(u32 a, u32 b){ return (u32)((u64)a * b % MOD_P); }

__device__ u32 powmod(u32 b, u32 e){
  u32 r = 1;
  while (e){ if (e & 1) r = mul64mod(r, b); b = mul64mod(b, b); e >>= 1; }
  return r;
}

__device__ __forceinline__ u32 shoup_of(u32 v){ return (u32)(((u64)v << 32) / MOD_P); }

// reduce a in [0,2P) to [0,P): v_sub + v_min_u32 (unsigned-wrap min trick)
__device__ __forceinline__ u32 redP(u32 a){
  u32 b = a - MOD_P;
  return b < a ? b : a;
}

// Shoup modular multiply; valid for ANY a < 2^32 (w < P): r = a*w mod P in [0,P)
__device__ __forceinline__ u32 mul_shoup(u32 a, uint2 t){
  u32 q = __umulhi(a, t.y);
  u32 r = a * t.x - q * MOD_P;          // exact mod 2^32, true value < 2P
  return redP(r);
}

__device__ __forceinline__ constexpr int rev4(int m){
  return ((m&1)<<3) | ((m&2)<<1) | ((m&4)>>1) | ((m&8)>>3);
}

// DIF butterfly: (x,y) -> (x+y mod P, (x-y)*t mod P); inputs in [0,P)
__device__ __forceinline__ void bf(u32 &x, u32 &y, uint2 t){
  u32 s = redP(x + y);
  u32 d = x - y + MOD_P;                // in (0,2P) — mul_shoup absorbs
  x = s; y = mul_shoup(d, t);
}
// last stage, twiddle=1: y left in [0,2P) (consumer must absorb or redP)
__device__ __forceinline__ void bf0(u32 &x, u32 &y){
  u32 s = redP(x + y);
  u32 d = x - y + MOD_P;
  x = s; y = d;
}

// phase-1: thread rows r = b + 8m (m=0..15), DIF stages h=64,32,16,8
__device__ __forceinline__ void stages_p1(u32 v[16], int b, const uint2* __restrict__ twl){
  #pragma unroll
  for (int m = 0; m < 8; ++m) bf(v[m], v[m+8], twl[b + 8*m]);               // s=6
  #pragma unroll
  for (int g = 0; g < 2; ++g)
    #pragma unroll
    for (int m = 0; m < 4; ++m) bf(v[g*8+m], v[g*8+m+4], twl[(b + 8*m) << 1]); // s=5
  #pragma unroll
  for (int g = 0; g < 4; ++g)
    #pragma unroll
    for (int m = 0; m < 2; ++m) bf(v[g*4+m], v[g*4+m+2], twl[(b + 8*m) << 2]); // s=4
  #pragma unroll
  for (int k = 0; k < 8; ++k) bf(v[2*k], v[2*k+1], twl[b << 3]);            // s=3
}
// phase-2: thread rows r = 16b + m, DIF stages h=4,2,1
__device__ __forceinline__ void stages_p2(u32 v[16], const uint2* __restrict__ twl){
  #pragma unroll
  for (int g = 0; g < 2; ++g)
    #pragma unroll
    for (int m = 0; m < 4; ++m) bf(v[g*8+m], v[g*8+m+4], twl[m << 4]);      // s=2
  #pragma unroll
  for (int g = 0; g < 4; ++g)
    #pragma unroll
    for (int m = 0; m < 2; ++m) bf(v[g*4+m], v[g*4+m+2], twl[m << 5]);      // s=1
  #pragma unroll
  for (int k = 0; k < 8; ++k) bf0(v[2*k], v[2*k+1]);                        // s=0 (e=0)
}

// LDS swizzle for pass C tile [row=jc(128)][col=ka(128)]: 2-way max aliasing
__device__ __forceinline__ int cidx(int row, int a){
  return (row << 7) | (a ^ (row >> 2));
}

// ------------- table generation: ONE powmod per thread, 257 WGs -------------
extern "C" __global__ void k_gen(uint2* __restrict__ tw, const int* __restrict__ f_intt){
  const u32 tid = blockIdx.x * 256 + threadIdx.x;
  const int intt = f_intt[0];
  const u32 MASK = (1u << 21) - 1;
  u32 v; int dst;
  if (tid < 16384){                       // T_A: w^{hi*lo}
    u32 e = (tid >> 7) * (tid & 127);
    if (intt) e = ((1u<<21) - e) & MASK;
    v = powmod(31u, 960u * e); dst = T_A + tid;
  } else if (tid < 32768){                // T_B: w^{128*hi*lo mod 2^21}
    u32 i = tid - 16384;
    u32 e = (((i >> 7) * (i & 127)) << 7) & MASK;
    if (intt) e = ((1u<<21) - e) & MASK;
    v = powmod(31u, 960u * e); dst = T_B + i;
  } else if (tid < 49152){                // T_W128P: w^{128 i mod 2^21}
    u32 i = tid - 32768;
    u32 e = (i << 7) & MASK;
    if (intt) e = ((1u<<21) - e) & MASK;
    v = powmod(31u, 960u * e); dst = T_W128P + i;
  } else if (tid < 65536){                // T_CLP: c^i (c=7 or 7^-1)
    u32 i = tid - 49152;
    v = intt ? powmod(7u, (MOD_P - 1 - i) % (MOD_P - 1)) : powmod(7u, i);
    dst = T_CLP + i;
  } else if (tid < 65664){                // T_CHP: c^{i<<14}
    u32 e = (tid - 65536) << 14;
    v = intt ? powmod(7u, MOD_P - 1 - e) : powmod(7u, e);
    dst = T_CHP + (tid - 65536);
  } else if (tid < 65728){                // T_RP: w^{i<<14}
    u32 e = ((tid - 65664) << 14) & MASK;
    if (intt) e = ((1u<<21) - e) & MASK;
    v = powmod(31u, 960u * e); dst = T_RP + (tid - 65664);
  } else if (tid == 65728){               // NINV
    v = powmod(1u << 21, MOD_P - 2); dst = T_NINV;
  } else return;
  tw[dst] = make_uint2(v, shoup_of(v));
}

// ---- pass A (z-path): NTT over ja; strided READ, CONTIGUOUS write to z -----
// z layout: z[batch][jb][ka][jc] -> contiguous 64KB per WG
extern "C" __global__ void __launch_bounds__(1024, 8) k_passA_z(
    const u32* __restrict__ x, u32* __restrict__ z, const uint2* __restrict__ tw,
    const int* __restrict__ f_intt, const int* __restrict__ f_coset)
{
  __shared__ u32 lds[16384];              // [128 ja][128 jc] natural
  const int wg = blockIdx.x;
  const int jb = wg & 127;
  const int batch = wg >> 7;
  const int t = threadIdx.x;
  const u32* xb = x + ((size_t)batch << 21) + (jb << 7);
  u32* zb = z + ((size_t)batch << 21) + (jb << 14);
  const uint2* twl = tw + T_RP;
  {   // stage-in: issue ALL loads first, then LDS writes (max loads in flight)
    const int q = t & 31, rr = t >> 5;    // q: jc-quad, rr: 0..31
    uint4 tmp[4];
    #pragma unroll
    for (int i = 0; i < 4; ++i)
      tmp[i] = *(const uint4*)(xb + ((size_t)(rr + 32*i) << 14) + (q << 2));
    #pragma unroll
    for (int i = 0; i < 4; ++i){
      u32* d = &lds[((rr + 32*i) << 7) | (q << 2)];
      d[0] = redP(tmp[i].x); d[1] = redP(tmp[i].y);
      d[2] = redP(tmp[i].z); d[3] = redP(tmp[i].w);
    }
  }
  __syncthreads();
  const int jc = t & 127;
  const int b = __builtin_amdgcn_readfirstlane(t >> 7);   // 0..7, wave-uniform
  u32 v[16];
  #pragma unroll
  for (int m = 0; m < 16; ++m) v[m] = lds[((b + 8*m) << 7) | jc];
  if ((f_intt[0] == 0) && (f_coset[0] != 0)){
    uint2 cl = tw[T_CLP + (jb << 7) + jc];
    #pragma unroll
    for (int m = 0; m < 16; ++m){
      v[m] = mul_shoup(v[m], cl);
      v[m] = mul_shoup(v[m], tw[T_CHP + b + 8*m]);
    }
  }
  stages_p1(v, b, twl);
  #pragma unroll
  for (int m = 0; m < 16; ++m) lds[((b + 8*m) << 7) | jc] = v[m];
  __syncthreads();
  #pragma unroll
  for (int m = 0; m < 16; ++m) v[m] = lds[((16*b + m) << 7) | jc];
  stages_p2(v, twl);
  const int rb = ((b&1)<<2) | (b&2) | ((b&4)>>2);          // rev3(b)
  #pragma unroll
  for (int m = 0; m < 16; ++m){
    const int ka = (rev4(m) << 3) | rb;                    // br7(16b+m)
    u32 vv = mul_shoup(v[m], tw[T_A + (ka << 7) + jc]);    // absorbs [0,2P)
    vv = mul_shoup(vv, tw[T_W128P + ka * jb]);             // wave-uniform
    zb[(ka << 7) + jc] = vv;                               // contiguous block
  }
}

// ---- pass B (z-path): strided READ from z, contiguous write to y -----------
extern "C" __global__ void __launch_bounds__(1024, 8) k_passB_z(
    const u32* __restrict__ z, u32* __restrict__ y, const uint2* __restrict__ tw)
{
  __shared__ u32 lds[16384];              // [128 jb][128 jc]
  const int wg = blockIdx.x;
  const int ka = wg & 127;
  const int batch = wg >> 7;
  const int t = threadIdx.x;
  const u32* zb = z + ((size_t)batch << 21) + (ka << 7);
  u32* yb = y + ((size_t)batch << 21) + ((size_t)ka << 14);
  const uint2* twl = tw + T_RP;
  {   // stage-in: z[jb<<14 + ka<<7 + jc] -> 512B segments stride 64KB
    const int q = t & 31, rr = t >> 5;
    uint4 tmp[4];
    #pragma unroll
    for (int i = 0; i < 4; ++i)
      tmp[i] = *(const uint4*)(zb + ((size_t)(rr + 32*i) << 14) + (q << 2));
    #pragma unroll
    for (int i = 0; i < 4; ++i){
      u32* d = &lds[((rr + 32*i) << 7) | (q << 2)];
      d[0] = tmp[i].x; d[1] = tmp[i].y; d[2] = tmp[i].z; d[3] = tmp[i].w;
    }
  }
  __syncthreads();
  const int jc = t & 127;
  const int b = __builtin_amdgcn_readfirstlane(t >> 7);
  u32 v[16];
  #pragma unroll
  for (int m = 0; m < 16; ++m) v[m] = lds[((b + 8*m) << 7) | jc];
  stages_p1(v, b, twl);
  #pragma unroll
  for (int m = 0; m < 16; ++m) lds[((b + 8*m) << 7) | jc] = v[m];
  __syncthreads();
  #pragma unroll
  for (int m = 0; m < 16; ++m) v[m] = lds[((16*b + m) << 7) | jc];
  stages_p2(v, twl);
  const int rb = ((b&1)<<2) | (b&2) | ((b&4)>>2);
  #pragma unroll
  for (int m = 0; m < 16; ++m){
    const int kb = (rev4(m) << 3) | rb;
    u32 vv = mul_shoup(v[m], tw[T_B + (kb << 7) + jc]);    // absorbs [0,2P)
    yb[(kb << 7) + jc] = vv;                               // contiguous slab
  }
}

// ---------------- fallback pass A (round-8 proven): x -> y strided ----------
extern "C" __global__ void __launch_bounds__(1024, 8) k_passA(
    const u32* __restrict__ x, u32* __restrict__ y, const uint2* __restrict__ tw,
    const int* __restrict__ f_intt, const int* __restrict__ f_coset)
{
  __shared__ u32 lds[16384];
  const int wg = blockIdx.x;
  const int jb = wg & 127;
  const int batch = wg >> 7;
  const int t = threadIdx.x;
  const u32* xb = x + ((size_t)batch << 21) + (jb << 7);
  u32* yb = y + ((size_t)batch << 21);
  const uint2* twl = tw + T_RP;
  {
    const int q = t & 31, rr = t >> 5;
    uint4 tmp[4];
    #pragma unroll
    for (int i = 0; i < 4; ++i)
      tmp[i] = *(const uint4*)(xb + ((size_t)(rr + 32*i) << 14) + (q << 2));
    #pragma unroll
    for (int i = 0; i < 4; ++i){
      u32* d = &lds[((rr + 32*i) << 7) | (q << 2)];
      d[0] = redP(tmp[i].x); d[1] = redP(tmp[i].y);
      d[2] = redP(tmp[i].z); d[3] = redP(tmp[i].w);
    }
  }
  __syncthreads();
  const int jc = t & 127;
  const int b = __builtin_amdgcn_readfirstlane(t >> 7);
  u32 v[16];
  #pragma unroll
  for (int m = 0; m < 16; ++m) v[m] = lds[((b + 8*m) << 7) | jc];
  if ((f_intt[0] == 0) && (f_coset[0] != 0)){
    uint2 cl = tw[T_CLP + (jb << 7) + jc];
    #pragma unroll
    for (int m = 0; m < 16; ++m){
      v[m] = mul_shoup(v[m], cl);
      v[m] = mul_shoup(v[m], tw[T_CHP + b + 8*m]);
    }
  }
  stages_p1(v, b, twl);
  #pragma unroll
  for (int m = 0; m < 16; ++m) lds[((b + 8*m) << 7) | jc] = v[m];
  __syncthreads();
  #pragma unroll
  for (int m = 0; m < 16; ++m) v[m] = lds[((16*b + m) << 7) | jc];
  stages_p2(v, twl);
  const int rb = ((b&1)<<2) | (b&2) | ((b&4)>>2);
  #pragma unroll
  for (int m = 0; m < 16; ++m){
    const int ka = (rev4(m) << 3) | rb;
    u32 vv = mul_shoup(v[m], tw[T_A + (ka << 7) + jc]);
    vv = mul_shoup(vv, tw[T_W128P + ka * jb]);
    yb[((size_t)ka << 14) + (jb << 7) + jc] = vv;
  }
}

// ---------------- fallback pass B (round-8 proven): y in-place --------------
extern "C" __global__ void __launch_bounds__(1024, 8) k_passB(
    u32* __restrict__ y, const uint2* __restrict__ tw)
{
  __shared__ u32 lds[16384];
  const int wg = blockIdx.x;
  const int ka = wg & 127;
  const int batch = wg >> 7;
  const int t = threadIdx.x;
  u32* yb = y + ((size_t)batch << 21) + ((size_t)ka << 14);
  const uint2* twl = tw + T_RP;
  {
    const uint4* s4 = (const uint4*)yb;
    uint4* l4 = (uint4*)lds;
    #pragma unroll
    for (int i = 0; i < 4; ++i) l4[t + 1024*i] = s4[t + 1024*i];
  }
  __syncthreads();
  const int jc = t & 127;
  const int b = __builtin_amdgcn_readfirstlane(t >> 7);
  u32 v[16];
  #pragma unroll
  for (int m = 0; m < 16; ++m) v[m] = lds[((b + 8*m) << 7) | jc];
  stages_p1(v, b, twl);
  #pragma unroll
  for (int m = 0; m < 16; ++m) lds[((b + 8*m) << 7) | jc] = v[m];
  __syncthreads();
  #pragma unroll
  for (int m = 0; m < 16; ++m) v[m] = lds[((16*b + m) << 7) | jc];
  stages_p2(v, twl);
  const int rb = ((b&1)<<2) | (b&2) | ((b&4)>>2);
  #pragma unroll
  for (int m = 0; m < 16; ++m){
    const int kb = (rev4(m) << 3) | rb;
    u32 vv = mul_shoup(v[m], tw[T_B + (kb << 7) + jc]);
    yb[(kb << 7) + jc] = vv;
  }
}

// ------- pass C: NTT over jc + in-place plane transpose to final order ------
extern "C" __global__ void __launch_bounds__(1024, 8) k_passC(
    u32* __restrict__ y, const uint2* __restrict__ tw,
    const int* __restrict__ f_intt, const int* __restrict__ f_coset)
{
  __shared__ u32 lds[16384];
  const int wg = blockIdx.x;
  const int kb = wg & 127;
  const int batch = wg >> 7;
  u32* yb = y + ((size_t)batch << 21);
  const u32* base = yb + (kb << 7);
  const int t = threadIdx.x;
  {   // stage-in: issue all loads, then swizzled LDS transpose writes
    const int q = t & 31;
    const int rr = t >> 5;
    uint4 tmp[4];
    #pragma unroll
    for (int i = 0; i < 4; ++i)
      tmp[i] = *(const uint4*)(base + ((size_t)(rr + 32*i) << 14) + (q << 2));
    #pragma unroll
    for (int i = 0; i < 4; ++i){
      int kaL = rr + 32*i;
      lds[cidx(4*q+0, kaL)] = tmp[i].x;
      lds[cidx(4*q+1, kaL)] = tmp[i].y;
      lds[cidx(4*q+2, kaL)] = tmp[i].z;
      lds[cidx(4*q+3, kaL)] = tmp[i].w;
    }
  }
  __syncthreads();
  const int a = t & 127;
  const int b = __builtin_amdgcn_readfirstlane(t >> 7);
  const uint2* twl = tw + T_RP;
  u32 v[16];
  #pragma unroll
  for (int m = 0; m < 16; ++m) v[m] = lds[cidx(b + 8*m, a)];
  stages_p1(v, b, twl);
  #pragma unroll
  for (int m = 0; m < 16; ++m) lds[cidx(b + 8*m, a)] = v[m];
  __syncthreads();
  #pragma unroll
  for (int m = 0; m < 16; ++m) v[m] = lds[cidx(16*b + m, a)];
  stages_p2(v, twl);
  const int rb = ((b&1)<<2) | (b&2) | ((b&4)>>2);
  const int intt = f_intt[0];
  const int coset = f_coset[0];
  #pragma unroll
  for (int m = 0; m < 16; ++m){
    const int kc = (rev4(m) << 3) | rb;
    u32 vv = v[m];
    if (intt){
      vv = mul_shoup(vv, tw[T_NINV]);
      if (coset){
        vv = mul_shoup(vv, tw[T_CLP + (kb << 7) + a]);
        vv = mul_shoup(vv, tw[T_CHP + kc]);
      }
    } else {
      vv = redP(vv);
    }
    __builtin_nontemporal_store(vv, yb + ((size_t)kc << 14) + (kb << 7) + a);
  }
}

extern "C" void kernel_launch(void* const* d_in, const int* in_sizes, int n_in,
                              void* d_out, int out_size, void* d_ws, size_t ws_size,
                              hipStream_t stream)
{
  const u32* x = (const u32*)d_in[0];
  const int* f_intt  = (const int*)d_in[1];
  const int* f_coset = (const int*)d_in[2];
  u32* y   = (u32*)d_out;
  uint2* tw = (uint2*)d_ws;
  const int batch = in_sizes[0] >> 21;     // 8
  const int nwg = batch << 7;              // 1024 workgroups per pass

  k_gen<<<257, 256, 0, stream>>>(tw, f_intt);

  const size_t zoff = (size_t)1 << 20;                 // tables live in [0,1MB)
  const size_t need = zoff + ((size_t)batch << 23);    // + 64MB scratch
  if (ws_size >= need){
    u32* z = (u32*)((char*)d_ws + zoff);
    k_passA_z<<<nwg, 1024, 0, stream>>>(x, z, tw, f_intt, f_coset);
    k_passB_z<<<nwg, 1024, 0, stream>>>(z, y, tw);
  } else {
    k_passA<<<nwg, 1024, 0, stream>>>(x, y, tw, f_intt, f_coset);
    k_passB<<<nwg, 1024, 0, stream>>>(y, tw);
  }
  k_passC<<<nwg, 1024, 0, stream>>>(y, tw, f_intt, f_coset);
}